// Round 12
// baseline (207.231 us; speedup 1.0000x reference)
//
#include <hip/hip_runtime.h>
#include <hip/hip_bf16.h>

#define BATCH   16384
#define NSTEPS  100
#define DT_     0.01f
#define SQRTDT  0.1f
#define SIGMA0_ 0.5f
#define TSTRIDE 144   // halfwords per t-table step row (pad: breaks parity bank clash)

typedef _Float16  f16x2  __attribute__((ext_vector_type(2)));
typedef _Float16  f16x4  __attribute__((ext_vector_type(4)));
typedef _Float16  f16x8  __attribute__((ext_vector_type(8)));
typedef __fp16    h16x2  __attribute__((ext_vector_type(2)));
typedef float     f32x4  __attribute__((ext_vector_type(4)));

__global__ void zero_out_kernel(float* out) { if (threadIdx.x == 0) out[0] = 0.0f; }

static __device__ __forceinline__ f16x4 pk4(const f32x4& d) {
    union { h16x2 h[2]; f16x4 v; } c;
    c.h[0] = __builtin_amdgcn_cvt_pkrtz(d[0], d[1]);
    c.h[1] = __builtin_amdgcn_cvt_pkrtz(d[2], d[3]);
    return c.v;
}

struct N3 { float a, b, c; };
union HU { unsigned short u; _Float16 h; };

// R12: 3 waves/SIMD at CONSTANT total work via z double-stepping.
// MFMA B-frag columns are independent -> z-wave packs (8 paths x 2 steps)
// into its 16 columns: cols 0-7 = step i, cols 8-15 = step i+1 (both y's
// from the q-ring; z-steps independent given y). z-waves: 8 paths, 50
// passes; per-pass work identical to R11's z-step -> chip-total work
// unchanged, wave count 2048 z + 1024 q = 3072 = 3/SIMD (R5 proved wave
// overlap is the only lever that moved the floor; R10's 3-wave failure was
// split-MLP overhead + 2-producer polls, both absent here).
// Per-lane deltas: t-table row += (ln15>>3); noise (step,path) per lane;
// terminal shfl_xor(Ysum,8) rejoins even/odd-step partials.
// Block = 384 thr (w0,w1 = q for groups 0,1; w2..w5 = z halves), grid 512.
__launch_bounds__(384, 3)
__global__ void deepbsde_kernel(
    const float* __restrict__ y0,  const float* __restrict__ Y0,
    const float* __restrict__ zW1, const float* __restrict__ zb1,
    const float* __restrict__ zW2, const float* __restrict__ zb2,
    const float* __restrict__ zW3, const float* __restrict__ zb3,
    const float* __restrict__ qW1, const float* __restrict__ qb1,
    const float* __restrict__ qW2, const float* __restrict__ qb2,
    const float* __restrict__ qW3, const float* __restrict__ qb3,
    const float* __restrict__ dW,  const float* __restrict__ dZ,
    float* __restrict__ out)
{
    __shared__ __align__(16) _Float16 tbl[NSTEPS * TSTRIDE];   // 28.8 KB
    __shared__ unsigned short yh_ring[2][NSTEPS + 1][16];      // 6.5 KB
    __shared__ float ffin[2][16], yTfin[2][16];
    __shared__ int   flags[2];

    const int tid  = threadIdx.x;
    const int lane = tid & 63;
    const int w    = tid >> 6;           // 0..5
    const bool isQ = (w < 2);
    const int g    = isQ ? w : ((w - 2) >> 1);   // group 0/1
    const int half = (w - 2) & 1;                // z-wave path half
    const int ln15 = lane & 15, q4 = lane >> 4;
    const int gw   = (blockIdx.x << 1) + g;
    const int pbase = gw << 4;           // 16 paths per group

    const float y0v = y0[0], Y0v = Y0[0];
    if (tid < 2) flags[tid] = 0;
    if (tid < 32) { HU hu; hu.h = (_Float16)y0v; yh_ring[tid >> 4][0][tid & 15] = hu.u; }

    // ---- one-time t-table (A1*t + C1, both MLPs), accumulated tt ----
    {
        float tt = 0.0f;
        for (int i = 0; i < NSTEPS; ++i) {
            int r = tid - ((i % 6) << 6);
            if (r >= 0 && r < 64) {
                int q4e = r >> 4, mlp_ = (r >> 3) & 1, m = r & 7;
                const float* Wp = mlp_ ? qW1 : zW1;
                const float* bp = mlp_ ? qb1 : zb1;
                int i0 = 2*m, i1 = 2*m + 1;
                int k0 = 32*(i0 >> 3) + 8*q4e + (i0 & 7);
                int k1 = 32*(i1 >> 3) + 8*q4e + (i1 & 7);
                _Float16 th = (_Float16)tt;
                f16x2 A = {(_Float16)Wp[k0], (_Float16)Wp[k1]};
                f16x2 C = {(_Float16)bp[k0], (_Float16)bp[k1]};
                f16x2 tv = {th, th};
                f16x2 v = A*tv + C;
                int hw = i*TSTRIDE + q4e*32 + mlp_*16 + 2*m;
                *(f16x2*)&tbl[hw] = v;
            }
            tt += DT_;
        }
    }

    // ---- role-selected weights ----
    const float* W1p = isQ ? qW1 : zW1;
    const float* W2p = isQ ? qW2 : zW2;
    const float* b2p = isQ ? qb2 : zb2;

    f16x2 B1[8];
#pragma unroll
    for (int m = 0; m < 8; ++m) {
        int i0 = 2*m, i1 = 2*m + 1;
        int k0 = 32*(i0 >> 3) + 8*q4 + (i0 & 7);
        int k1 = 32*(i1 >> 3) + 8*q4 + (i1 & 7);
        B1[m] = (f16x2){(_Float16)W1p[64 + k0], (_Float16)W1p[64 + k1]};
    }
    f16x8 Af[4][2];
#pragma unroll
    for (int tN = 0; tN < 4; ++tN)
#pragma unroll
        for (int f = 0; f < 2; ++f)
#pragma unroll
            for (int j = 0; j < 8; ++j) {
                int k = 32*f + 8*q4 + j, n = 16*tN + ln15;
                Af[tN][f][j] = (_Float16)W2p[k*64 + n];
            }
    f32x4 b2v[4];
#pragma unroll
    for (int tN = 0; tN < 4; ++tN)
#pragma unroll
        for (int r = 0; r < 4; ++r)
            b2v[tN][r] = b2p[16*tN + 4*q4 + r];

    const int c3 = ln15 & 3;
    f16x8 A3[2];
#pragma unroll
    for (int fl = 0; fl < 2; ++fl)
#pragma unroll
        for (int j = 0; j < 8; ++j) {
            int tN = 2*fl + (j >> 2);
            int n  = 16*tN + 4*q4 + (j & 3);
            float wv = isQ ? ((c3 == 3) ? qW3[n]                 : 0.0f)
                           : ((c3 < 3)  ? SQRTDT * zW3[n*3 + c3] : 0.0f);
            A3[fl][j] = (_Float16)wv;
        }
    const f32x4 C3b = isQ ? (f32x4){0.0f, 0.0f, 0.0f, qb3[0]}
                          : (f32x4){SQRTDT*zb3[0], SQRTDT*zb3[1], SQRTDT*zb3[2], 0.0f};

    const float CSIG = SIGMA0_ * SQRTDT;
    const float NHDT = -0.5f * DT_;
    const f16x2 zero2h = {(_Float16)0.0f, (_Float16)0.0f};
    const f16x4 zero4h = {(_Float16)0.0f, (_Float16)0.0f, (_Float16)0.0f, (_Float16)0.0f};

    __syncthreads();   // table + flags + y0 visible; ONLY block-wide sync

    if (!isQ) {
        // ===== z-wave: 8 paths x 2 steps per pass; 50 passes =====
        const int sodd = ln15 >> 3;                 // step offset of this column
        const int prow = 8*half + (ln15 & 7);       // ring/path column
        float Ysum = 0.0f, acc = 0.0f;

        auto loadNW = [&](int k, N3& d) {           // noise for pass k, this lane
            int s = 2*k + sodd; if (s > NSTEPS - 1) s = NSTEPS - 1;
            const float* p = dW + ((size_t)s * BATCH + pbase + prow) * 3;
            d.a = p[0]; d.b = p[1]; d.c = p[2];
        };
        auto loadNZ = [&](int k, N3& d) {
            int s = 2*k + sodd; if (s > NSTEPS - 1) s = NSTEPS - 1;
            const float* p = dZ + ((size_t)s * BATCH + pbase + prow) * 3;
            d.a = p[0]; d.b = p[1]; d.c = p[2];
        };

        f16x8 tc0, tc1, td0, td1;                   // t-table ping-pong (per-lane addr)
        { const f16x8* tp = (const f16x8*)(tbl + sodd*TSTRIDE + q4*32); tc0 = tp[0]; tc1 = tp[1]; }

        auto zpass = [&](int k, unsigned short yu, const N3& nw, const N3& nz,
                         f16x8& t0, f16x8& t1, f16x8& u0, f16x8& u1) {
            int kp = k + 1; if (kp > 49) kp = 49;
            { const f16x8* tp = (const f16x8*)(tbl + (2*kp + sodd)*TSTRIDE + q4*32);
              u0 = tp[0]; u1 = tp[1]; }

            HU hu; hu.u = yu;
            const f16x2 yv = {hu.h, hu.h};
            union U8 { f16x8 v; f16x2 h[4]; };
            U8 T0; T0.v = t0; U8 T1; T1.v = t1;
            union { f16x2 h[4]; f16x8 v; } b0, b1;
#pragma unroll
            for (int m = 0; m < 4; ++m) {
                b0.h[m] = __builtin_elementwise_max((f16x2)(B1[m]*yv   + T0.h[m]), zero2h);
                b1.h[m] = __builtin_elementwise_max((f16x2)(B1[m+4]*yv + T1.h[m]), zero2h);
            }
            union { f16x4 q[4]; f16x8 o[2]; } Bh;
#pragma unroll
            for (int tN = 0; tN < 4; ++tN) {
                f32x4 d = b2v[tN];
                d = __builtin_amdgcn_mfma_f32_16x16x32_f16(Af[tN][0], b0.v, d, 0, 0, 0);
                d = __builtin_amdgcn_mfma_f32_16x16x32_f16(Af[tN][1], b1.v, d, 0, 0, 0);
                Bh.q[tN] = __builtin_elementwise_max(pk4(d), zero4h);
            }
            f32x4 P = C3b;
            P = __builtin_amdgcn_mfma_f32_16x16x32_f16(A3[0], Bh.o[0], P, 0, 0, 0);
            P = __builtin_amdgcn_mfma_f32_16x16x32_f16(A3[1], Bh.o[1], P, 0, 0, 0);

            float zdw = fmaf(P[2], nw.c, fmaf(P[1], nw.b, P[0]*nw.a));
            float zdz = fmaf(P[2], nz.c, fmaf(P[1], nz.b, P[0]*nz.a));
            Ysum += zdw;
            float r = zdw - zdz;
            acc = fmaf(r, r, acc);
        };

        // prologue: y for batch 0 (steps 0..3) + noise for passes 0..3
        unsigned short yu0, yu1, eu0, eu1;
        {
            volatile int* qf = &flags[g];
            while (*qf < 4) { }
            yu0 = *(volatile unsigned short*)&yh_ring[g][0 + sodd][prow];
            yu1 = *(volatile unsigned short*)&yh_ring[g][2 + sodd][prow];
        }
        N3 s0w, s0z, s1w, s1z, s2w, s2z, s3w, s3z;
        loadNW(0, s0w); loadNZ(0, s0z); loadNW(1, s1w); loadNZ(1, s1z);
        loadNW(2, s2w); loadNZ(2, s2z); loadNW(3, s3w); loadNZ(3, s3z);

#pragma unroll 1
        for (int b = 0; b < 25; ++b) {              // batch = 2 passes = 4 steps
            int k0_ = 2*b;
            if (b < 24) {                           // prefetch next batch's y
                volatile int* qf = &flags[g];
                while (*qf < 4*b + 8) { }
                eu0 = *(volatile unsigned short*)&yh_ring[g][4*b + 4 + sodd][prow];
                eu1 = *(volatile unsigned short*)&yh_ring[g][4*b + 6 + sodd][prow];
            }
            if ((b & 1) == 0) {
                zpass(k0_,     yu0, s0w, s0z, tc0, tc1, td0, td1);
                loadNW(k0_ + 4, s0w); loadNZ(k0_ + 4, s0z);
                zpass(k0_ + 1, yu1, s1w, s1z, td0, td1, tc0, tc1);
                loadNW(k0_ + 5, s1w); loadNZ(k0_ + 5, s1z);
            } else {
                zpass(k0_,     yu0, s2w, s2z, tc0, tc1, td0, td1);
                loadNW(k0_ + 4, s2w); loadNZ(k0_ + 4, s2z);
                zpass(k0_ + 1, yu1, s3w, s3z, td0, td1, tc0, tc1);
                loadNW(k0_ + 5, s3w); loadNZ(k0_ + 5, s3z);
            }
            yu0 = eu0; yu1 = eu1;
        }

        // terminal: rejoin even/odd-step partial sums, add terminal loss
        { volatile int* qf = &flags[g]; while (*qf < NSTEPS + 1) { } }
        float Ys2 = Ysum + __shfl_xor(Ysum, 8);
        if (sodd == 0) {
            float Fq = *(volatile float*)&ffin[g][prow];
            float yT = *(volatile float*)&yTfin[g][prow];
            float Yvf = Y0v + Fq + Ys2;
            float dterm = Yvf - yT*yT;
            acc = fmaf(dterm, dterm, acc);
        }
        float val = (q4 == 0) ? acc : 0.0f;
#pragma unroll
        for (int off = 1; off < 64; off <<= 1) val += __shfl_xor(val, off);
        if (lane == 0) atomicAdd(out, val * (1.0f / BATCH));
    } else {
        // ===== q-wave: serial y-recurrence; publish-only (R11 unchanged) =====
        __builtin_amdgcn_s_setprio(1);
        float y = y0v, Facc = 0.0f;
        f16x8 c0, c1, d0, d1;
        { const f16x8* tp = (const f16x8*)(tbl + q4*32); c0 = tp[2]; c1 = tp[3]; }

        auto loadW16 = [&](int i, N3& d) {
            int ic = (i < NSTEPS) ? i : NSTEPS - 1;
            const float* p = dW + ((size_t)ic * BATCH + pbase + ln15) * 3;
            d.a = p[0]; d.b = p[1]; d.c = p[2];
        };

        auto qstep = [&](int j, const N3& nw, f16x8& t0, f16x8& t1, f16x8& u0, f16x8& u1) {
            int jp = j + 1; jp = (jp > NSTEPS - 1) ? NSTEPS - 1 : jp;
            { const f16x8* tp = (const f16x8*)(tbl + jp*TSTRIDE + q4*32); u0 = tp[2]; u1 = tp[3]; }

            _Float16 yh = (_Float16)y;
            const f16x2 yv = {yh, yh};
            union U8 { f16x8 v; f16x2 h[4]; };
            U8 T0; T0.v = t0; U8 T1; T1.v = t1;
            union { f16x2 h[4]; f16x8 v; } b0, b1;
#pragma unroll
            for (int m = 0; m < 4; ++m) {
                b0.h[m] = __builtin_elementwise_max((f16x2)(B1[m]*yv   + T0.h[m]), zero2h);
                b1.h[m] = __builtin_elementwise_max((f16x2)(B1[m+4]*yv + T1.h[m]), zero2h);
            }
            union { f16x4 q[4]; f16x8 o[2]; } Bh;
#pragma unroll
            for (int tN = 0; tN < 4; ++tN) {
                f32x4 d = b2v[tN];
                d = __builtin_amdgcn_mfma_f32_16x16x32_f16(Af[tN][0], b0.v, d, 0, 0, 0);
                d = __builtin_amdgcn_mfma_f32_16x16x32_f16(Af[tN][1], b1.v, d, 0, 0, 0);
                Bh.q[tN] = __builtin_elementwise_max(pk4(d), zero4h);
            }
            f32x4 Pv = C3b;
            Pv = __builtin_amdgcn_mfma_f32_16x16x32_f16(A3[0], Bh.o[0], Pv, 0, 0, 0);
            Pv = __builtin_amdgcn_mfma_f32_16x16x32_f16(A3[1], Bh.o[1], Pv, 0, 0, 0);

            float qv = Pv[3];
            float snw = (nw.a + nw.b) + nw.c;
            Facc = fmaf(NHDT*qv, qv, Facc);
            y = fmaf(CSIG, snw, fmaf(qv, DT_, y));
            if (q4 == 0) {
                HU hu; hu.h = (_Float16)y;
                *(volatile unsigned short*)&yh_ring[g][j + 1][ln15] = hu.u;
            }
        };

        N3 n0,n1,n2,n3,n4,n5,n6,n7;
        loadW16(0,n0); loadW16(1,n1); loadW16(2,n2); loadW16(3,n3);
        loadW16(4,n4); loadW16(5,n5); loadW16(6,n6); loadW16(7,n7);

#pragma unroll 1
        for (int k = 0; k < 12; ++k) {
            int j = 8*k;
            qstep(j,     n0, c0, c1, d0, d1);  loadW16(j + 8,  n0);
            qstep(j + 1, n1, d0, d1, c0, c1);  loadW16(j + 9,  n1);
            qstep(j + 2, n2, c0, c1, d0, d1);  loadW16(j + 10, n2);
            qstep(j + 3, n3, d0, d1, c0, c1);  loadW16(j + 11, n3);
            __builtin_amdgcn_s_waitcnt(0xC07F);        // y writes landed
            if (lane == 0) *(volatile int*)&flags[g] = j + 4;
            qstep(j + 4, n4, c0, c1, d0, d1);  loadW16(j + 12, n4);
            qstep(j + 5, n5, d0, d1, c0, c1);  loadW16(j + 13, n5);
            qstep(j + 6, n6, c0, c1, d0, d1);  loadW16(j + 14, n6);
            qstep(j + 7, n7, d0, d1, c0, c1);  loadW16(j + 15, n7);
            __builtin_amdgcn_s_waitcnt(0xC07F);
            if (lane == 0) *(volatile int*)&flags[g] = j + 8;
        }
        // tail: steps 96..99 in slots 0..3
        qstep(96, n0, c0, c1, d0, d1);
        qstep(97, n1, d0, d1, c0, c1);
        qstep(98, n2, c0, c1, d0, d1);
        qstep(99, n3, d0, d1, c0, c1);
        __builtin_amdgcn_s_waitcnt(0xC07F);            // y(100) landed
        if (lane == 0) *(volatile int*)&flags[g] = NSTEPS;

        if (q4 == 0) {
            *(volatile float*)&ffin[g][ln15]  = Facc;
            *(volatile float*)&yTfin[g][ln15] = y;     // y(NSTEPS) in f32
        }
        __builtin_amdgcn_s_waitcnt(0xC07F);
        if (lane == 0) *(volatile int*)&flags[g] = NSTEPS + 1;
    }
}

extern "C" void kernel_launch(void* const* d_in, const int* in_sizes, int n_in,
                              void* d_out, int out_size, void* d_ws, size_t ws_size,
                              hipStream_t stream)
{
    zero_out_kernel<<<1, 64, 0, stream>>>((float*)d_out);
    deepbsde_kernel<<<512, 384, 0, stream>>>(
        (const float*)d_in[0],  (const float*)d_in[1],
        (const float*)d_in[2],  (const float*)d_in[3],
        (const float*)d_in[4],  (const float*)d_in[5],
        (const float*)d_in[6],  (const float*)d_in[7],
        (const float*)d_in[8],  (const float*)d_in[9],
        (const float*)d_in[10], (const float*)d_in[11],
        (const float*)d_in[12], (const float*)d_in[13],
        (const float*)d_in[14], (const float*)d_in[15],
        (float*)d_out);
}